// Round 4
// baseline (450.777 us; speedup 1.0000x reference)
//
#include <hip/hip_runtime.h>
#include <hip/hip_bf16.h>
#include <stdint.h>

#define B_N   16384
#define L_N   63
#define K2LOG2E 2.8853900817779268f   // 2*log2(e)
#define LOG2E   1.4426950408889634f

typedef unsigned int   u32;
typedef unsigned short u16;
typedef __attribute__((ext_vector_type(8))) __bf16 bf16x8;
typedef __attribute__((ext_vector_type(4))) float  f32x4;

__device__ __forceinline__ u16 f2b(float f){
  u32 u = __builtin_bit_cast(u32, f);
  u += 0x7fffu + ((u >> 16) & 1u);
  return (u16)(u >> 16);
}
__device__ __forceinline__ u32 pk_bf16(float lo, float hi){
  u32 r;
  asm("v_cvt_pk_bf16_f32 %0, %1, %2" : "=v"(r) : "v"(lo), "v"(hi));
  return r;
}
// tanh(a): 5 ops, saturation-safe
__device__ __forceinline__ float tanh_pre(float a){
  float t = __builtin_amdgcn_exp2f(a * K2LOG2E);
  float r = __builtin_amdgcn_rcpf(t + 1.0f);
  return fmaf(-2.0f, r, 1.0f);
}
// tanh(acc + b) with bb = b*K2LOG2E pre-scaled (bias rides the fma)
__device__ __forceinline__ float tanh_b(float acc, float bb){
  float t = __builtin_amdgcn_exp2f(fmaf(acc, K2LOG2E, bb));
  float r = __builtin_amdgcn_rcpf(t + 1.0f);
  return fmaf(-2.0f, r, 1.0f);
}

// ---- merged weight conversion (one block per layer l) ----
// W1[l][d][n] (masked d<=l) -> w1t[l][n][64], col63 = b1  (x col63 = 1)
// W2[l][h][n]               -> w2t[l][n][128]   (transpose)
__global__ void k_conv_w(const float* __restrict__ W1, const float* __restrict__ b1,
                         const float* __restrict__ W2,
                         u16* __restrict__ w1t, u16* __restrict__ w2t){
  __shared__ u16 t[16384];
  const int l = blockIdx.x, tid = threadIdx.x;
  // --- W1 ---
  #pragma unroll
  for (int i = 0; i < 32; ++i) t[i*256 + tid] = 0;
  __syncthreads();
  for (int i = 0; i < 32; ++i){
    int idx = i*256 + tid;              // idx = d*128 + n (coalesced)
    if (idx < 63*128){
      int d = idx >> 7, n = idx & 127;
      if (d <= l) t[n*64 + d] = f2b(W1[(l*63 + d)*128 + n]);
    }
  }
  if (tid < 128) t[tid*64 + 63] = f2b(b1[l*128 + tid]);
  __syncthreads();
  {
    uint4* o = (uint4*)(w1t + l*(128*64));
    const uint4* s4 = (const uint4*)t;
    #pragma unroll
    for (int i = 0; i < 4; ++i) o[i*256 + tid] = s4[i*256 + tid];
  }
  __syncthreads();
  // --- W2 ---
  #pragma unroll
  for (int i = 0; i < 64; ++i){
    int idx = i*256 + tid;              // idx = h*128 + n (coalesced)
    int h = idx >> 7, n = idx & 127;
    t[n*128 + h] = f2b(W2[l*16384 + idx]);
  }
  __syncthreads();
  {
    uint4* o = (uint4*)(w2t + l*(128*128));
    const uint4* s4 = (const uint4*)t;
    #pragma unroll
    for (int i = 0; i < 8; ++i) o[i*256 + tid] = s4[i*256 + tid];
  }
}

// ---- x f32 -> bf16, col63 := 1.0 (bias lane for stage 1) ----
__global__ void k_conv_x(const float* __restrict__ x, u16* __restrict__ out){
  int idx = blockIdx.x*256 + threadIdx.x;
  float4 v = ((const float4*)x)[idx];
  ushort4 r;
  r.x = f2b(v.x); r.y = f2b(v.y); r.z = f2b(v.z);
  r.w = ((idx & 15) == 15) ? (u16)0x3F80 : f2b(v.w);
  ((ushort4*)out)[idx] = r;
}

// ---- main: block = 128 batch rows x layer l; 4 waves, wave owns h-rows
// [32wv,32wv+32). ONE barrier (h1 exchange). Stage-3 partials -> atomicAdd.
__global__ __launch_bounds__(256, 4)
void k_main(const u16* __restrict__ W1T, const u16* __restrict__ W2T,
            const u16* __restrict__ xbf, const float* __restrict__ b2,
            const float* __restrict__ W3,
            float* __restrict__ mu, float* __restrict__ alpha)
{
  __shared__ __align__(16) u16 h1[128*128];   // [b][h], XOR-swizzled rows, 32KB
  const int tid = threadIdx.x;
  const int l  = blockIdx.y;
  const int bx = blockIdx.x;
  const int wv = tid >> 6;
  const int ln = tid & 63;
  const int c  = ln & 15;
  const int g  = ln >> 4;
  const int rowbase = bx*128;
  const int sx = (c & 7) << 4;         // row-swizzle XOR (b&7 == c&7)
  char* const h1b = (char*)h1;

  const u16* w1p = W1T + l*(128*64);
  const u16* w2p = W2T + l*(128*128);

  // ---- stage 1: h1T[h][b] = tanh(W1T . xT)  (b1 in col 63, x col63 = 1) ----
  f32x4 acc[2][8] = {};
  #pragma unroll
  for (int s = 0; s < 2; ++s){
    bf16x8 a0 = *(const bf16x8*)(w1p + ((2*wv+0)*16 + c)*64 + s*32 + g*8);
    bf16x8 a1 = *(const bf16x8*)(w1p + ((2*wv+1)*16 + c)*64 + s*32 + g*8);
    #pragma unroll
    for (int bt = 0; bt < 8; ++bt){
      bf16x8 xf = *(const bf16x8*)(xbf + (size_t)(rowbase + bt*16 + c)*64 + s*32 + g*8);
      acc[0][bt] = __builtin_amdgcn_mfma_f32_16x16x32_bf16(a0, xf, acc[0][bt], 0,0,0);
      acc[1][bt] = __builtin_amdgcn_mfma_f32_16x16x32_bf16(a1, xf, acc[1][bt], 0,0,0);
    }
  }

  // epilogue 1: tanh, pack, swizzled 8B store into h1[b][h]
  #pragma unroll
  for (int m = 0; m < 2; ++m){
    int h0 = (2*wv+m)*16 + g*4;
    #pragma unroll
    for (int bt = 0; bt < 8; ++bt){
      u32 p0 = pk_bf16(tanh_pre(acc[m][bt][0]), tanh_pre(acc[m][bt][1]));
      u32 p1 = pk_bf16(tanh_pre(acc[m][bt][2]), tanh_pre(acc[m][bt][3]));
      int b = bt*16 + c;
      *(uint2*)(h1b + b*256 + ((h0*2) ^ sx)) = make_uint2(p0, p1);
    }
  }
  __syncthreads();

  // ---- stage 2: h2T[n][b] = tanh(W2T . h1T + b2) ----
  f32x4 acc2[2][8] = {};
  #pragma unroll
  for (int s = 0; s < 4; ++s){
    bf16x8 a0 = *(const bf16x8*)(w2p + ((2*wv+0)*16 + c)*128 + s*32 + g*8);
    bf16x8 a1 = *(const bf16x8*)(w2p + ((2*wv+1)*16 + c)*128 + s*32 + g*8);
    #pragma unroll
    for (int bt = 0; bt < 8; ++bt){
      int b = bt*16 + c;
      bf16x8 hf = *(const bf16x8*)(h1b + b*256 + ((s*64 + g*16) ^ sx));
      acc2[0][bt] = __builtin_amdgcn_mfma_f32_16x16x32_bf16(a0, hf, acc2[0][bt], 0,0,0);
      acc2[1][bt] = __builtin_amdgcn_mfma_f32_16x16x32_bf16(a1, hf, acc2[1][bt], 0,0,0);
    }
  }

  // epilogue 2 + stage 3: tanh(acc2+b2), dot W3, per-wave k-partial
  float part[8][2] = {};
  #pragma unroll
  for (int m = 0; m < 2; ++m){
    int n0 = (2*wv+m)*16 + g*4;
    float bb[4], w30[4], w31[4];
    #pragma unroll
    for (int r = 0; r < 4; ++r){
      bb[r] = b2[l*128 + n0 + r] * K2LOG2E;
      float2 w3v = ((const float2*)W3)[l*128 + n0 + r];
      w30[r] = w3v.x; w31[r] = w3v.y;
    }
    #pragma unroll
    for (int bt = 0; bt < 8; ++bt)
      #pragma unroll
      for (int r = 0; r < 4; ++r){
        float h2 = tanh_b(acc2[m][bt][r], bb[r]);
        part[bt][0] = fmaf(h2, w30[r], part[bt][0]);
        part[bt][1] = fmaf(h2, w31[r], part[bt][1]);
      }
  }
  // reduce the 4 g-groups, then one atomic per (row, output)
  #pragma unroll
  for (int bt = 0; bt < 8; ++bt){
    #pragma unroll
    for (int o = 0; o < 2; ++o){
      float v = part[bt][o];
      v += __shfl_xor(v, 16, 64);
      v += __shfl_xor(v, 32, 64);
      part[bt][o] = v;
    }
  }
  if (g == 0){
    #pragma unroll
    for (int bt = 0; bt < 8; ++bt){
      int row = rowbase + bt*16 + c;
      atomicAdd(mu    + (size_t)row*64 + l + 1, part[bt][0]);
      atomicAdd(alpha + (size_t)row*64 + l + 1, part[bt][1]);
    }
  }
}

// ---- finalize: z = (x-(mu+b3_0))*exp(-(alpha+b3_1)), reversed; logdet ----
__global__ void k_fin(const float* __restrict__ x, const float* __restrict__ mu,
                      const float* __restrict__ alpha, const float* __restrict__ b3,
                      const float* __restrict__ ip, float* __restrict__ out)
{
  int row = blockIdx.x*4 + (threadIdx.x >> 6);
  int d   = threadIdx.x & 63;
  float xv = x[(size_t)row*64 + d];
  float m, a;
  if (d == 0){ m = ip[0]; a = ip[1]; }
  else {
    m = mu[(size_t)row*64 + d]    + b3[(d-1)*2 + 0];
    a = alpha[(size_t)row*64 + d] + b3[(d-1)*2 + 1];
  }
  float z = (xv - m) * __builtin_amdgcn_exp2f(-a * LOG2E);
  out[(size_t)row*64 + 63 - d] = z;
  float s = a;
  #pragma unroll
  for (int off = 32; off; off >>= 1) s += __shfl_xor(s, off, 64);
  if (d == 0) out[(size_t)B_N*64 + row] = -s;
}

extern "C" void kernel_launch(void* const* d_in, const int* in_sizes, int n_in,
                              void* d_out, int out_size, void* d_ws, size_t ws_size,
                              hipStream_t stream)
{
  const float* x  = (const float*)d_in[0];
  const float* W1 = (const float*)d_in[1];
  const float* b1 = (const float*)d_in[2];
  const float* W2 = (const float*)d_in[3];
  const float* b2 = (const float*)d_in[4];
  const float* W3 = (const float*)d_in[5];
  const float* b3 = (const float*)d_in[6];
  const float* ip = (const float*)d_in[7];

  char* ws = (char*)d_ws;
  // w1t 1MB | w2t 2MB | xbf 2MB | mu 4MB | alpha 4MB = 13MB
  u16*   w1t  = (u16*)(ws);
  u16*   w2t  = (u16*)(ws + 1048576);
  u16*   xbf  = (u16*)(ws + 3145728);
  float* mu   = (float*)(ws + 5242880);
  float* alph = (float*)(ws + 9437184);
  if (ws_size < 13631488) return;  // fail visibly rather than corrupt

  k_conv_w<<<L_N, 256, 0, stream>>>(W1, b1, W2, w1t, w2t);
  k_conv_x<<<(B_N*64/4)/256, 256, 0, stream>>>(x, xbf);
  hipMemsetAsync(mu, 0, 8388608, stream);   // zero mu+alpha (contiguous)

  dim3 grid(B_N/128, L_N);
  k_main<<<grid, 256, 0, stream>>>(w1t, w2t, xbf, b2, W3, mu, alph);

  k_fin<<<B_N/4, 256, 0, stream>>>(x, mu, alph, b3, ip, (float*)d_out);
}

// Round 5
// 149.361 us; speedup vs baseline: 3.0180x; 3.0180x over previous
//
#include <hip/hip_runtime.h>
#include <hip/hip_bf16.h>
#include <stdint.h>

#define B_N   16384
#define L_N   63
#define K2LOG2E 2.8853900817779268f   // 2*log2(e)
#define LOG2E   1.4426950408889634f

typedef unsigned int   u32;
typedef unsigned short u16;
typedef __attribute__((ext_vector_type(8))) __bf16 bf16x8;
typedef __attribute__((ext_vector_type(4))) float  f32x4;

__device__ __forceinline__ u16 f2b(float f){
  u32 u = __builtin_bit_cast(u32, f);
  u += 0x7fffu + ((u >> 16) & 1u);
  return (u16)(u >> 16);
}
__device__ __forceinline__ u32 pk_bf16(float lo, float hi){
  u32 r;
  asm("v_cvt_pk_bf16_f32 %0, %1, %2" : "=v"(r) : "v"(lo), "v"(hi));
  return r;
}
// tanh(a): 3 VALU + 2 trans, saturation-safe
__device__ __forceinline__ float tanh_pre(float a){
  float t = __builtin_amdgcn_exp2f(a * K2LOG2E);
  float r = __builtin_amdgcn_rcpf(t + 1.0f);
  return fmaf(-2.0f, r, 1.0f);
}
// tanh(acc + b) with bb pre-scaled by K2LOG2E
__device__ __forceinline__ float tanh_b(float acc, float bb){
  float t = __builtin_amdgcn_exp2f(fmaf(acc, K2LOG2E, bb));
  float r = __builtin_amdgcn_rcpf(t + 1.0f);
  return fmaf(-2.0f, r, 1.0f);
}

// ---- merged weight conversion (one block per layer l) ----
// W1[l][d][n] (masked d<=l) -> w1t[l][n][64], col63 = b1  (x col63 = 1)
// W2[l][h][n]               -> w2t[l][n][128]   (transpose)
__global__ void k_conv_w(const float* __restrict__ W1, const float* __restrict__ b1,
                         const float* __restrict__ W2,
                         u16* __restrict__ w1t, u16* __restrict__ w2t){
  __shared__ u16 t[16384];
  const int l = blockIdx.x, tid = threadIdx.x;
  #pragma unroll
  for (int i = 0; i < 32; ++i) t[i*256 + tid] = 0;
  __syncthreads();
  for (int i = 0; i < 32; ++i){
    int idx = i*256 + tid;              // idx = d*128 + n (coalesced)
    if (idx < 63*128){
      int d = idx >> 7, n = idx & 127;
      if (d <= l) t[n*64 + d] = f2b(W1[(l*63 + d)*128 + n]);
    }
  }
  if (tid < 128) t[tid*64 + 63] = f2b(b1[l*128 + tid]);
  __syncthreads();
  {
    uint4* o = (uint4*)(w1t + l*(128*64));
    const uint4* s4 = (const uint4*)t;
    #pragma unroll
    for (int i = 0; i < 4; ++i) o[i*256 + tid] = s4[i*256 + tid];
  }
  __syncthreads();
  #pragma unroll
  for (int i = 0; i < 64; ++i){
    int idx = i*256 + tid;              // idx = h*128 + n (coalesced)
    int h = idx >> 7, n = idx & 127;
    t[n*128 + h] = f2b(W2[l*16384 + idx]);
  }
  __syncthreads();
  {
    uint4* o = (uint4*)(w2t + l*(128*128));
    const uint4* s4 = (const uint4*)t;
    #pragma unroll
    for (int i = 0; i < 8; ++i) o[i*256 + tid] = s4[i*256 + tid];
  }
}

// ---- x f32 -> bf16, col63 := 1.0 (bias lane for stage 1) ----
__global__ void k_conv_x(const float* __restrict__ x, u16* __restrict__ out){
  int idx = blockIdx.x*256 + threadIdx.x;
  float4 v = ((const float4*)x)[idx];
  ushort4 r;
  r.x = f2b(v.x); r.y = f2b(v.y); r.z = f2b(v.z);
  r.w = ((idx & 15) == 15) ? (u16)0x3F80 : f2b(v.w);
  ((ushort4*)out)[idx] = r;
}

// ---- main: block = 128 batch rows x layer l; 4 waves own h-row M-tiles.
// 2 barriers. Tail fuses z-store; alpha saved for logdet kernel. No atomics.
__global__ __launch_bounds__(256, 4)
void k_main(const u16* __restrict__ W1T, const u16* __restrict__ W2T,
            const u16* __restrict__ xbf, const float* __restrict__ x,
            const float* __restrict__ b2, const float* __restrict__ W3,
            const float* __restrict__ b3,
            float* __restrict__ out, float* __restrict__ alph)
{
  __shared__ __align__(16) u16 h1[128*128];   // [b][h] swizzled, 32KB
  __shared__ float2 sc[4][128];               // stage-3 partials, 4KB
  const int tid = threadIdx.x;
  const int l  = blockIdx.y;
  const int bx = blockIdx.x;
  const int wv = tid >> 6;
  const int ln = tid & 63;
  const int c  = ln & 15;
  const int g  = ln >> 4;
  const int rowbase = bx*128;
  const int sx = (c & 7) << 4;         // row-swizzle XOR ((b&7)==(c&7))
  char* const h1b = (char*)h1;

  const u16* w1p = W1T + l*(128*64);
  const u16* w2p = W2T + l*(128*128);

  // ---- stage 1: h1T[h][b] = tanh(W1T . xT)  (b1 in col 63, x col63 = 1) ----
  bf16x8 a1f[2][2];
  #pragma unroll
  for (int m = 0; m < 2; ++m)
    #pragma unroll
    for (int s = 0; s < 2; ++s)
      a1f[m][s] = *(const bf16x8*)(w1p + ((2*wv+m)*16 + c)*64 + s*32 + g*8);

  f32x4 acc[2][8] = {};
  #pragma unroll
  for (int s = 0; s < 2; ++s)
    #pragma unroll
    for (int bt = 0; bt < 8; ++bt){
      bf16x8 xf = *(const bf16x8*)(xbf + (size_t)(rowbase + bt*16 + c)*64 + s*32 + g*8);
      acc[0][bt] = __builtin_amdgcn_mfma_f32_16x16x32_bf16(a1f[0][s], xf, acc[0][bt], 0,0,0);
      acc[1][bt] = __builtin_amdgcn_mfma_f32_16x16x32_bf16(a1f[1][s], xf, acc[1][bt], 0,0,0);
    }

  // epilogue 1: tanh, pack, swizzled 8B store into h1[b][h]
  #pragma unroll
  for (int m = 0; m < 2; ++m){
    int h0 = (2*wv+m)*16 + g*4;
    #pragma unroll
    for (int bt = 0; bt < 8; ++bt){
      u32 p0 = pk_bf16(tanh_pre(acc[m][bt][0]), tanh_pre(acc[m][bt][1]));
      u32 p1 = pk_bf16(tanh_pre(acc[m][bt][2]), tanh_pre(acc[m][bt][3]));
      int b = bt*16 + c;
      *(uint2*)(h1b + b*256 + ((h0*2) ^ sx)) = make_uint2(p0, p1);
    }
  }
  __syncthreads();

  // ---- stage 2: h2T[n][b] = W2T . h1T ----
  f32x4 acc2[2][8] = {};
  #pragma unroll
  for (int s = 0; s < 4; ++s){
    bf16x8 a0 = *(const bf16x8*)(w2p + ((2*wv+0)*16 + c)*128 + s*32 + g*8);
    bf16x8 a1 = *(const bf16x8*)(w2p + ((2*wv+1)*16 + c)*128 + s*32 + g*8);
    #pragma unroll
    for (int bt = 0; bt < 8; ++bt){
      int b = bt*16 + c;
      bf16x8 hf = *(const bf16x8*)(h1b + b*256 + ((s*64 + g*16) ^ sx));
      acc2[0][bt] = __builtin_amdgcn_mfma_f32_16x16x32_bf16(a0, hf, acc2[0][bt], 0,0,0);
      acc2[1][bt] = __builtin_amdgcn_mfma_f32_16x16x32_bf16(a1, hf, acc2[1][bt], 0,0,0);
    }
  }

  // epilogue 2 + stage 3: tanh(acc2+b2), dot W3, per-wave partials
  float part[8][2] = {};
  #pragma unroll
  for (int m = 0; m < 2; ++m){
    int q = (2*wv+m)*4 + g;                      // row-quad index n0/4
    float4 bbv = ((const float4*)(b2 + l*128))[q];
    float4 w3a = ((const float4*)(W3 + l*256))[q*2 + 0];  // rows n0,n0+1
    float4 w3b = ((const float4*)(W3 + l*256))[q*2 + 1];  // rows n0+2,n0+3
    float bb[4]  = { bbv.x*K2LOG2E, bbv.y*K2LOG2E, bbv.z*K2LOG2E, bbv.w*K2LOG2E };
    float w30[4] = { w3a.x, w3a.z, w3b.x, w3b.z };
    float w31[4] = { w3a.y, w3a.w, w3b.y, w3b.w };
    #pragma unroll
    for (int bt = 0; bt < 8; ++bt)
      #pragma unroll
      for (int r = 0; r < 4; ++r){
        float h2 = tanh_b(acc2[m][bt][r], bb[r]);
        part[bt][0] = fmaf(h2, w30[r], part[bt][0]);
        part[bt][1] = fmaf(h2, w31[r], part[bt][1]);
      }
  }
  #pragma unroll
  for (int bt = 0; bt < 8; ++bt)
    #pragma unroll
    for (int o = 0; o < 2; ++o){
      float v = part[bt][o];
      v += __shfl_xor(v, 16, 64);
      v += __shfl_xor(v, 32, 64);
      part[bt][o] = v;
    }
  if (g == 0){
    #pragma unroll
    for (int bt = 0; bt < 8; ++bt)
      sc[wv][bt*16 + c] = make_float2(part[bt][0], part[bt][1]);
  }
  __syncthreads();

  // tail: finish mu/alpha, fuse z-store (reversed), save alpha for logdet
  if (tid < 128){
    int row = rowbase + tid;
    float2 s0 = sc[0][tid], s1 = sc[1][tid], s2 = sc[2][tid], s3 = sc[3][tid];
    float muv = s0.x + s1.x + s2.x + s3.x + b3[l*2 + 0];
    float alv = s0.y + s1.y + s2.y + s3.y + b3[l*2 + 1];
    float xv  = x[(size_t)row*64 + l + 1];
    out[(size_t)row*64 + 62 - l] = (xv - muv) * __builtin_amdgcn_exp2f(-alv * LOG2E);
    alph[(size_t)row*64 + l + 1] = alv;
  }
}

// ---- finalize: z column 63 (d=0 term) + logdet row-reduce ----
__global__ void k_fin(const float* __restrict__ x, const float* __restrict__ alph,
                      const float* __restrict__ ip, float* __restrict__ out)
{
  int row = blockIdx.x*4 + (threadIdx.x >> 6);
  int d   = threadIdx.x & 63;
  float a = (d == 0) ? ip[1] : alph[(size_t)row*64 + d];
  float s = a;
  #pragma unroll
  for (int off = 32; off; off >>= 1) s += __shfl_xor(s, off, 64);
  if (d == 0){
    out[(size_t)row*64 + 63] = (x[(size_t)row*64] - ip[0]) * __builtin_amdgcn_exp2f(-a * LOG2E);
    out[(size_t)B_N*64 + row] = -s;
  }
}

extern "C" void kernel_launch(void* const* d_in, const int* in_sizes, int n_in,
                              void* d_out, int out_size, void* d_ws, size_t ws_size,
                              hipStream_t stream)
{
  const float* x  = (const float*)d_in[0];
  const float* W1 = (const float*)d_in[1];
  const float* b1 = (const float*)d_in[2];
  const float* W2 = (const float*)d_in[3];
  const float* b2 = (const float*)d_in[4];
  const float* W3 = (const float*)d_in[5];
  const float* b3 = (const float*)d_in[6];
  const float* ip = (const float*)d_in[7];

  char* ws = (char*)d_ws;
  // w1t 1MB | w2t 2MB | xbf 2MB | alpha 4MB = 9MB
  u16*   w1t  = (u16*)(ws);
  u16*   w2t  = (u16*)(ws + 1048576);
  u16*   xbf  = (u16*)(ws + 3145728);
  float* alph = (float*)(ws + 5242880);
  if (ws_size < 9437184) return;  // fail visibly rather than corrupt

  k_conv_w<<<L_N, 256, 0, stream>>>(W1, b1, W2, w1t, w2t);
  k_conv_x<<<(B_N*64/4)/256, 256, 0, stream>>>(x, xbf);

  dim3 grid(B_N/128, L_N);
  k_main<<<grid, 256, 0, stream>>>(w1t, w2t, xbf, x, b2, W3, b3,
                                   (float*)d_out, alph);

  k_fin<<<B_N/4, 256, 0, stream>>>(x, alph, ip, (float*)d_out);
}